// Round 11
// baseline (175.440 us; speedup 1.0000x reference)
//
#include <hip/hip_runtime.h>

#define B_DIM 8192
#define NOUT  1024
#define KDIM  2048
#define SLOT  24576

typedef __bf16 bf16x8 __attribute__((ext_vector_type(8)));
typedef float  f32x4  __attribute__((ext_vector_type(4)));

__device__ __forceinline__ unsigned short f2bf(float f) {
  unsigned int u = __float_as_uint(f);
  u += 0x7fff + ((u >> 16) & 1);   // RNE
  return (unsigned short)(u >> 16);
}
__device__ __forceinline__ float sigmoid_f(float x) {
  return 1.0f / (1.0f + __expf(-x));
}
__device__ __forceinline__ float tanh_f(float x) {
  return 1.0f - 2.0f / (__expf(2.0f * x) + 1.0f);
}
__device__ __forceinline__ void gload_lds16(const void* g, void* l) {
  __builtin_amdgcn_global_load_lds(
      (const __attribute__((address_space(1))) void*)g,
      (__attribute__((address_space(3))) void*)l, 16, 0, 0);
}

// gate-interleaved weight column index (R9-verified): one wave's 64-ci strip
// holds all 4 gates of 16 nouts; ni fragment index == gate.
__device__ __forceinline__ int cimap(int g, int n) {
  return ((n >> 4) << 6) | ((g & 3) << 4) | (n & 15);
}

// ---------------- kernel 1: pack xh = concat(x, out_tm1) as bf16 ------------
__global__ void pack_xh_kernel(const float* __restrict__ x,
                               const float* __restrict__ h,
                               unsigned short* __restrict__ xh) {
  const long total = (long)B_DIM * KDIM / 4;
  for (long i = (long)blockIdx.x * blockDim.x + threadIdx.x; i < total;
       i += (long)gridDim.x * blockDim.x) {
    long e = i * 4;
    int b = (int)(e >> 11);
    int c = (int)(e & 2047);
    float4 v = (c < 1024)
        ? *reinterpret_cast<const float4*>(x + (long)b * 1024 + c)
        : *reinterpret_cast<const float4*>(h + (long)b * 1024 + (c - 1024));
    ushort4 o;
    o.x = f2bf(v.x); o.y = f2bf(v.y); o.z = f2bf(v.z); o.w = f2bf(v.w);
    *reinterpret_cast<ushort4*>(xh + e) = o;
  }
}

// ------- kernel 2: wt[ci][k] = bf16(W_g[k][n]), ci = gate-interleaved -------
__global__ void transpose_w_kernel(const float* __restrict__ Wf,
                                   const float* __restrict__ Wi,
                                   const float* __restrict__ Wc,
                                   const float* __restrict__ Wo,
                                   unsigned short* __restrict__ wt) {
  __shared__ float tile[32][33];
  const int g = blockIdx.z;
  const float* W = (g == 0) ? Wf : (g == 1) ? Wi : (g == 2) ? Wc : Wo;
  const int n0 = blockIdx.x * 32;
  const int k0 = blockIdx.y * 32;
  const int tx = threadIdx.x, ty = threadIdx.y;
#pragma unroll
  for (int r = ty; r < 32; r += 8)
    tile[r][tx] = W[(long)(k0 + r) * NOUT + n0 + tx];
  __syncthreads();
#pragma unroll
  for (int r = ty; r < 32; r += 8) {
    int ci = cimap(g, n0 + r);
    wt[(long)ci * KDIM + k0 + tx] = f2bf(tile[tx][r]);
  }
}

// --- kernel 3: 128m x 256ci, BK=32, ring-3 24KB slots, 2 blocks/CU ---------
// Block = 256 threads = 4 waves (1 wave/SIMD); 72 KB LDS -> 2 blocks/CU with
// INDEPENDENT barriers -> block A's MFMA cluster overlaps block B's LDS/DMA
// phase (m114 overlap). Blocks' LDS regions are disjoint -> hazards stay
// intra-block; R10's ledger applies unchanged:
//   per K32-iter t: { 6 gload_lds stage(t+2 -> slot (t+2)%3) ; 12 ds_reads
//     (slot t%3) ; 32 MFMA (consume reads; compiler lgkm) ;
//     vmcnt(6) ; s_barrier }
// RAW: vmcnt(6) leaves only stage(t+2) outstanding -> stage(t+1) retired one
//   barrier before its reads (prologue: stage(0),stage(1); vmcnt(6); bar).
// WAR: reads(t) are MFMA-consumed (lgkm) before BAR(t); the overwrite of
//   slot(t) is stage(t+3) issued after BAR(t) release. Airtight.
// LDS layout (R10-verified, 0 conflicts): two 64-B rows per 128-B line;
//   (row r, granule g) -> line = r>>1, slot8 = (((r&1)<<2)|g) ^ (line&7).
//   Reads (row = 16*mi + (l&15), g = l>>4): 8 lanes/slot across all 32 banks.
//   Staging: linear dest (t*16); source inverse-swizzled:
//   v = (t&7)^((t>>3)&7); srow = (t>>3)*2 + (v>>2) (+64 per gload); scol=(v&3)*16.
#define SB() __builtin_amdgcn_sched_barrier(0);

#define LOAD_FRAGS(S)                                                       \
  _Pragma("unroll") for (int mi = 0; mi < 8; ++mi)                          \
    af[mi] = *reinterpret_cast<const bf16x8*>(                              \
        lds + (S)*SLOT + mi * 1024 + laneRC);                               \
  _Pragma("unroll") for (int ni = 0; ni < 4; ++ni)                          \
    bq[ni] = *reinterpret_cast<const bf16x8*>(                              \
        lds + (S)*SLOT + 8192 + wn * 4096 + ni * 1024 + laneRC);

#define STAGE6(WS, KT) {                                                    \
  const long kb_ = (long)(KT) * 64 + scol;                                  \
  const char* ab_ = xh_b + (m0 + srow0) * 4096 + kb_;                       \
  const char* bb_ = wt_b + (c0 + srow0) * 4096 + kb_;                       \
  gload_lds16(ab_,             lds + (WS)*SLOT +         t16);              \
  gload_lds16(ab_ +  64L*4096, lds + (WS)*SLOT + 4096  + t16);              \
  gload_lds16(bb_,             lds + (WS)*SLOT + 8192  + t16);              \
  gload_lds16(bb_ +  64L*4096, lds + (WS)*SLOT + 12288 + t16);              \
  gload_lds16(bb_ + 128L*4096, lds + (WS)*SLOT + 16384 + t16);              \
  gload_lds16(bb_ + 192L*4096, lds + (WS)*SLOT + 20480 + t16); }

#define MFMA32()                                                            \
  _Pragma("unroll") for (int mi = 0; mi < 8; ++mi)                          \
  _Pragma("unroll") for (int ni = 0; ni < 4; ++ni)                          \
    acc[mi][ni] = __builtin_amdgcn_mfma_f32_16x16x32_bf16(                  \
        af[mi], bq[ni], acc[mi][ni], 0, 0, 0);

#define ITER(RS, WS, KT)                                                    \
  STAGE6(WS, KT)                                                            \
  LOAD_FRAGS(RS)                                                            \
  __builtin_amdgcn_s_setprio(1);                                            \
  MFMA32()                                                                  \
  __builtin_amdgcn_s_setprio(0);                                            \
  asm volatile("s_waitcnt vmcnt(6)" ::: "memory");                          \
  SB()                                                                      \
  __builtin_amdgcn_s_barrier();                                             \
  SB()

__global__ __launch_bounds__(256, 2)
void lstm_gemm_kernel(const unsigned short* __restrict__ xh,
                      const unsigned short* __restrict__ wt,
                      const float* __restrict__ state,
                      const float* __restrict__ bfp,
                      const float* __restrict__ bip,
                      const float* __restrict__ bcp,
                      const float* __restrict__ bop,
                      float* __restrict__ out) {
  __shared__ __attribute__((aligned(128))) char lds[73728];   // 3 x 24 KB

  const int tid  = threadIdx.x;
  const int lane = tid & 63;
  const int wn   = tid >> 6;        // wave = 64-ci strip 0..3

  // XCD map (R6-style, FETCH-verified): each XCD gets 8 contiguous m-bands
  // x all 16 ci-blocks -> A slice 4 MB (L2-resident), B via L3.
  const int wgid = blockIdx.y * 16 + blockIdx.x;   // 1024 blocks
  const int swz  = (wgid & 7) * 128 + (wgid >> 3);
  const int by   = swz >> 4;                       // 0..63 m-band
  const int bx   = swz & 15;                       // 0..15 ci-block
  const long m0  = (long)by * 128;
  const long c0  = (long)bx * 256;

  // ---- fragment-read addressing (R10-verified 0-conflict) ----
  const int key    = (lane >> 1) & 7;
  const int slotsw = (((lane & 1) << 2) | (lane >> 4)) ^ key;
  const int laneRC = key * 128 + slotsw * 16;

  // ---- stage addressing: linear dest, inverse-swizzled source ----
  const int vsw   = (tid & 7) ^ ((tid >> 3) & 7);
  const int srow0 = ((tid >> 3) << 1) + (vsw >> 2);
  const int scol  = (vsw & 3) << 4;
  const int t16   = tid * 16;

  const char* xh_b = (const char*)xh;  // 4096 B rows
  const char* wt_b = (const char*)wt;  // 4096 B rows

  f32x4  acc[8][4] = {};   // [mi][ni = gate f,i,c,o]
  bf16x8 af[8];
  bf16x8 bq[4];

  // ---- prologue: stage k-tiles 0,1 into slots 0,1; retire tile 0; barrier
  STAGE6(0, 0)
  STAGE6(1, 1)
  asm volatile("s_waitcnt vmcnt(6)" ::: "memory");
  SB()
  __builtin_amdgcn_s_barrier();
  SB()

  // ---- main loop: K32-tiles 0..62 (21 x 3-unrolled), tail = tile 63
  for (int t = 0; t < 63; t += 3) {
    const int k3 = (t + 3 > 63) ? 63 : t + 3;
    const int k4 = (t + 4 > 63) ? 63 : t + 4;
    ITER(0, 2, t + 2)
    ITER(1, 0, k3)
    ITER(2, 1, k4)
  }
  // tail: tile 63 reads slot 0 (staged iter 61, retired by iter 62's vmcnt)
  LOAD_FRAGS(0)
  __builtin_amdgcn_s_setprio(1);
  MFMA32()
  __builtin_amdgcn_s_setprio(0);
  asm volatile("s_waitcnt vmcnt(0) lgkmcnt(0)" ::: "memory");  // drain dups
  SB()

  // ---- fused LSTM epilogue: 4 gates = the 4 ni fragments, lane-local
  const int   nout = (bx * 4 + wn) * 16 + (lane & 15);
  const int   rsub4 = (lane >> 4) << 2;
  const float bfv = bfp[nout], biv = bip[nout];
  const float bcv = bcp[nout], bov = bop[nout];
  float* out2 = out + (long)B_DIM * NOUT;
#pragma unroll
  for (int mi = 0; mi < 8; ++mi)
#pragma unroll
    for (int v = 0; v < 4; ++v) {
      const long row = m0 + mi * 16 + rsub4 + v;
      float fg = sigmoid_f(acc[mi][0][v] + bfv);
      float ig = sigmoid_f(acc[mi][1][v] + biv);
      float cg = tanh_f   (acc[mi][2][v] + bcv);
      float og = sigmoid_f(acc[mi][3][v] + bov);
      float st = state[row * NOUT + nout];
      float ns = st * fg + ig * cg;
      out [row * NOUT + nout] = og * tanh_f(ns);
      out2[row * NOUT + nout] = ns;
    }
}

extern "C" void kernel_launch(void* const* d_in, const int* in_sizes, int n_in,
                              void* d_out, int out_size, void* d_ws, size_t ws_size,
                              hipStream_t stream) {
  const float* x     = (const float*)d_in[0];
  const float* h     = (const float*)d_in[1];
  const float* state = (const float*)d_in[2];
  const float* Wf    = (const float*)d_in[3];
  const float* bfp   = (const float*)d_in[4];
  const float* Wi    = (const float*)d_in[5];
  const float* bip   = (const float*)d_in[6];
  const float* Wc    = (const float*)d_in[7];
  const float* bcp   = (const float*)d_in[8];
  const float* Wo    = (const float*)d_in[9];
  const float* bop   = (const float*)d_in[10];
  float* out = (float*)d_out;

  unsigned short* xh = (unsigned short*)d_ws;
  unsigned short* wt = (unsigned short*)((char*)d_ws + (size_t)B_DIM * KDIM * 2);

  hipLaunchKernelGGL(pack_xh_kernel, dim3(2048), dim3(256), 0, stream, x, h, xh);
  hipLaunchKernelGGL(transpose_w_kernel, dim3(NOUT / 32, KDIM / 32, 4),
                     dim3(32, 8), 0, stream, Wf, Wi, Wc, Wo, wt);
  hipLaunchKernelGGL(lstm_gemm_kernel, dim3(16, 64), dim3(256), 0, stream,
                     xh, wt, state, bfp, bip, bcp, bop, out);
}

// Round 14
// 171.619 us; speedup vs baseline: 1.0223x; 1.0223x over previous
//
#include <hip/hip_runtime.h>

#define B_DIM 8192
#define NOUT  1024
#define KDIM  2048

typedef __bf16 bf16x8 __attribute__((ext_vector_type(8)));
typedef float  f32x16 __attribute__((ext_vector_type(16)));
typedef unsigned short u16x8 __attribute__((ext_vector_type(8)));

__device__ __forceinline__ unsigned short f2bf(float f) {
  unsigned int u = __float_as_uint(f);
  u += 0x7fff + ((u >> 16) & 1);   // RNE
  return (unsigned short)(u >> 16);
}
__device__ __forceinline__ float sigmoid_f(float x) {
  return 1.0f / (1.0f + __expf(-x));
}
__device__ __forceinline__ float tanh_f(float x) {
  return 1.0f - 2.0f / (__expf(2.0f * x) + 1.0f);
}
__device__ __forceinline__ void gload_lds16(const void* g, void* l) {
  __builtin_amdgcn_global_load_lds(
      (const __attribute__((address_space(1))) void*)g,
      (__attribute__((address_space(3))) void*)l, 16, 0, 0);
}

// ---- fragment-tiled layouts -------------------------------------------------
// xh_t: A fragments. 16B-unit (Q, kt, ks, lane) at byte
//       Q*131072 + kt*4096 + ks*1024 + lane*16 ;
//       value = xh[Q*32 + (l&31)][kt*64 + ks*16 + (l>>5)*8 .. +8]
//       == exactly the mfma_32x32x16 A-operand for one (strip, ks).
// wt_t: B fragments, same shape with ci-strips P 0..127.
// ci map (per 64-ci group = 16 nouts x 4 gates):
//       ci = (n>>4)*64 + (g>>1)*32 + ((n&15)<<1) | (g&1)
//       -> strip P = (n>>4)*2 + (g>>1); col-in-strip = (n&15)*2 + (g&1).
//       So nf(=P&1) = g>>1 ({f,i} in nf0, {c,o} in nf1); col parity = g&1.

// ------------- kernel 1: pack xh = concat(x, out_tm1), fragment-tiled -------
__global__ void pack_xh_kernel(const float* __restrict__ x,
                               const float* __restrict__ h,
                               unsigned short* __restrict__ xh_t) {
  const int total = 1 << 21;   // 2,097,152 16B-units = 32 MB
  for (int u = blockIdx.x * blockDim.x + threadIdx.x; u < total;
       u += gridDim.x * blockDim.x) {
    const int l  = u & 63;
    const int ks = (u >> 6) & 3;
    const int kt = (u >> 8) & 31;
    const int Q  = u >> 13;
    const long row = Q * 32 + (l & 31);
    const int  k0  = kt * 64 + ks * 16 + (l >> 5) * 8;   // multiple of 8
    const float* src = (k0 < 1024) ? (x + row * 1024 + k0)
                                   : (h + row * 1024 + (k0 - 1024));
    const float4 v0 = *reinterpret_cast<const float4*>(src);
    const float4 v1 = *reinterpret_cast<const float4*>(src + 4);
    u16x8 o;
    o[0] = f2bf(v0.x); o[1] = f2bf(v0.y); o[2] = f2bf(v0.z); o[3] = f2bf(v0.w);
    o[4] = f2bf(v1.x); o[5] = f2bf(v1.y); o[6] = f2bf(v1.z); o[7] = f2bf(v1.w);
    *reinterpret_cast<u16x8*>(xh_t + (long)u * 8) = o;
  }
}

// ------------- kernel 2: wt_t = fragment-tiled bf16 transpose of W ----------
// BUGFIX vs R12/R13: store index used t*8 with t = ks*64 + l, double-counting
// ks (ks*512 appeared in both the block index and t*8) -> wt_t scrambled.
// Correct lane term is l*8.
__global__ void transpose_w_kernel(const float* __restrict__ Wf,
                                   const float* __restrict__ Wi,
                                   const float* __restrict__ Wc,
                                   const float* __restrict__ Wo,
                                   unsigned short* __restrict__ wt_t) {
  const int P  = blockIdx.x;        // ci-strip 0..127
  const int kt = blockIdx.y;        // 0..31
  const int t  = threadIdx.x;
  const int ks = t >> 6;
  const int l  = t & 63;
  const int col = l & 31;
  const int g   = ((P & 1) << 1) | (col & 1);
  const int n   = (P >> 1) * 16 + (col >> 1);
  const int k0  = kt * 64 + ks * 16 + (l >> 5) * 8;
  const float* W = (g == 0) ? Wf : (g == 1) ? Wi : (g == 2) ? Wc : Wo;
  u16x8 o;
#pragma unroll
  for (int j = 0; j < 8; ++j)
    o[j] = f2bf(W[(long)(k0 + j) * 1024 + n]);
  *reinterpret_cast<u16x8*>(
      wt_t + ((long)(P * 32 + kt) * 4 + ks) * 512 + l * 8) = o;
}

// --- kernel 3: 256x256x64 GEMM, mfma 32x32x16, frag-linear LDS + LSTM -------
// (structure = R12/R13, ledger audited; LDS dest pointers now wave-uniform
//  per m104 semantics -- HW appends lane*16.)
#define SB() __builtin_amdgcn_sched_barrier(0);

#define LOAD_AF(BUF, MFB)                                                    \
  _Pragma("unroll") for (int m2 = 0; m2 < 2; ++m2)                           \
  _Pragma("unroll") for (int ks = 0; ks < 4; ++ks)                           \
    af[m2][ks] = *reinterpret_cast<const bf16x8*>(                           \
        baseA + (BUF)*65536 + ((MFB) + m2) * 4096 + ks * 1024);

#define LOAD_BQ(BUF)                                                         \
  _Pragma("unroll") for (int nf = 0; nf < 2; ++nf)                           \
  _Pragma("unroll") for (int ks = 0; ks < 4; ++ks)                           \
    bq[nf][ks] = *reinterpret_cast<const bf16x8*>(                           \
        baseB + (BUF)*65536 + nf * 4096 + ks * 1024);

#define MFMA16(MFB)                                                          \
  _Pragma("unroll") for (int m2 = 0; m2 < 2; ++m2)                           \
  _Pragma("unroll") for (int nf = 0; nf < 2; ++nf)                           \
  _Pragma("unroll") for (int ks = 0; ks < 4; ++ks)                           \
    acc[(MFB) + m2][nf] = __builtin_amdgcn_mfma_f32_32x32x16_bf16(           \
        af[m2][ks], bq[nf][ks], acc[(MFB) + m2][nf], 0, 0, 0);

#define STAGE_PA(BUF, KT) {                                                  \
  const char* a_ = srcA_base + (long)(KT) * 4096;                            \
  gload_lds16(a_,        lds + (BUF)*65536 + dstA0);                         \
  gload_lds16(a_ + 1024, lds + (BUF)*65536 + dstA0 + 1024);                  \
  const char* b_ = srcB_base + (long)(KT) * 4096;                            \
  gload_lds16(b_,        lds + (BUF)*65536 + dstB);                          \
  gload_lds16(b_ + 1024, lds + (BUF)*65536 + dstB + 1024);                   \
  gload_lds16(b_ + 2048, lds + (BUF)*65536 + dstB + 2048);                   \
  gload_lds16(b_ + 3072, lds + (BUF)*65536 + dstB + 3072); }

#define STAGE_PB(BUF, KT) {                                                  \
  const char* a_ = srcA2_base + (long)(KT) * 4096;                           \
  gload_lds16(a_,        lds + (BUF)*65536 + dstA2);                         \
  gload_lds16(a_ + 1024, lds + (BUF)*65536 + dstA2 + 1024); }

#define ITER(BUF, KN)                                                        \
  LOAD_AF(BUF, 0)                                                            \
  LOAD_BQ(BUF)                                                               \
  STAGE_PA(1 - (BUF), KN)                                                    \
  asm volatile("s_waitcnt vmcnt(6) lgkmcnt(0)" ::: "memory");                \
  SB() __builtin_amdgcn_s_barrier(); SB()                                    \
  __builtin_amdgcn_s_setprio(1);                                             \
  MFMA16(0)                                                                  \
  __builtin_amdgcn_s_setprio(0);                                             \
  LOAD_AF(BUF, 2)                                                            \
  STAGE_PB(1 - (BUF), KN)                                                    \
  asm volatile("s_waitcnt vmcnt(2) lgkmcnt(0)" ::: "memory");                \
  SB() __builtin_amdgcn_s_barrier(); SB()                                    \
  __builtin_amdgcn_s_setprio(1);                                             \
  MFMA16(2)                                                                  \
  __builtin_amdgcn_s_setprio(0);

__global__ __launch_bounds__(512, 2)
void lstm_gemm_kernel(const unsigned short* __restrict__ xh_t,
                      const unsigned short* __restrict__ wt_t,
                      const float* __restrict__ state,
                      const float* __restrict__ bfp,
                      const float* __restrict__ bip,
                      const float* __restrict__ bcp,
                      const float* __restrict__ bop,
                      float* __restrict__ out) {
  __shared__ __attribute__((aligned(128))) char lds[131072];

  const int tid  = threadIdx.x;
  const int w    = tid >> 6;
  const int lane = tid & 63;
  const int wm   = w >> 2;      // 0..1
  const int wn   = w & 3;       // 0..3
  const int l16  = lane * 16;

  // XCD-aware swizzle (nwg = 512, divisible by 8; R6-verified)
  int wg = blockIdx.y * 16 + blockIdx.x;
  wg = (wg & 7) * 64 + (wg >> 3);
  const int bm = wg >> 4;       // 0..31
  const int bn = wg & 15;       // 0..15
  const long m0 = (long)bm * 256;

  // ---- read bases (lane-linear fragments: 2 lanes/bank, conflict-free) ----
  const char* baseA = lds + wm * 16384 + l16;            // + buf + mf*4096 + ks*1024
  const char* baseB = lds + 32768 + wn * 8192 + l16;     // + buf + nf*4096 + ks*1024

  // ---- stage constants (LDS dests wave-uniform; HW appends lane*16) ----
  const int sA   = ((w >> 1) < 2) ? (w >> 1) : (w >> 1) + 2;   // {0,1,4,5}
  const int ksA0 = (w & 1) * 2;
  const char* xh_tb = (const char*)xh_t;
  const char* wt_tb = (const char*)wt_t;
  const char* srcA_base  = xh_tb + (long)(bm * 8 + sA)     * 131072 + ksA0 * 1024 + l16;
  const char* srcA2_base = xh_tb + (long)(bm * 8 + sA + 2) * 131072 + ksA0 * 1024 + l16;
  const char* srcB_base  = wt_tb + (long)(bn * 8 + w)      * 131072 + l16;
  const int dstA0 = (sA * 4 + ksA0) * 1024;
  const int dstA2 = ((sA + 2) * 4 + ksA0) * 1024;
  const int dstB  = 32768 + w * 4096;

  f32x16 acc[4][2] = {};    // [mf][nf]
  bf16x8 af[2][4];
  bf16x8 bq[2][4];

  // ---- prologue: stage tile 0 fully into buf0; drain; barrier
  STAGE_PA(0, 0)
  STAGE_PB(0, 0)
  asm volatile("s_waitcnt vmcnt(0)" ::: "memory");
  SB() __builtin_amdgcn_s_barrier(); SB()

  for (int t = 0; t < 32; t += 2) {
    const int k1 = t + 1;
    const int k2 = (t + 2 > 31) ? 31 : t + 2;   // clamp: dup re-stage, unread
    ITER(0, k1)
    ITER(1, k2)
  }
  asm volatile("s_waitcnt vmcnt(0) lgkmcnt(0)" ::: "memory");
  SB()

  // ---- fused LSTM epilogue (R5's first-run-validated exchange scheme) ------
  // C/D (32x32): col = lane&31, row = (r&3) + 8*(r>>2) + 4*(lane>>5) [m74].
  // Lane pair (l, l^1) shares nout = (col>>1): even lane holds gates {f,c}
  // (even cols), odd holds {i,o}. Even lane computes rows 0-15 (low regs),
  // odd rows 16-31 (high regs); each sends its unused reg-half via
  // shfl_xor(1). All lanes store 8 rows -> coverage complete.
  const int par = lane & 1;
  const int kh  = lane >> 5;
  const int nout = bn * 64 + wn * 16 + ((lane & 31) >> 1);
  const float bfv = bfp[nout], biv = bip[nout];
  const float bcv = bcp[nout], bov = bop[nout];
  float* out2 = out + (long)B_DIM * NOUT;
#pragma unroll
  for (int mf = 0; mf < 4; ++mf)
#pragma unroll
    for (int rr = 0; rr < 8; ++rr) {
      const float a0  = acc[mf][0][rr];       // low regs: rows 0-15 region
      const float a0h = acc[mf][0][rr + 8];   // high regs: rows 16-31 region
      const float a1  = acc[mf][1][rr];
      const float a1h = acc[mf][1][rr + 8];
      // even lane keeps low regs, sends high; odd keeps high, sends low
      const float send0 = par ? a0 : a0h;
      const float keep0 = par ? a0h : a0;
      const float send1 = par ? a1 : a1h;
      const float keep1 = par ? a1h : a1;
      const float oth0 = __shfl_xor(send0, 1, 64);
      const float oth1 = __shfl_xor(send1, 1, 64);
      // even lane: keep = own even col = f/c ; oth = partner's i/o
      const float fpre = par ? oth0 : keep0;
      const float ipre = par ? keep0 : oth0;
      const float cpre = par ? oth1 : keep1;
      const float opre = par ? keep1 : oth1;
      const long row = m0 + (wm * 4 + mf) * 32 +
                       (rr & 3) + 8 * (rr >> 2) + 16 * par + 4 * kh;
      const float fg = sigmoid_f(fpre + bfv);
      const float ig = sigmoid_f(ipre + biv);
      const float cg = tanh_f   (cpre + bcv);
      const float og = sigmoid_f(opre + bov);
      const float st = state[row * NOUT + nout];
      const float ns = st * fg + ig * cg;
      out [row * NOUT + nout] = og * tanh_f(ns);
      out2[row * NOUT + nout] = ns;
    }
}

extern "C" void kernel_launch(void* const* d_in, const int* in_sizes, int n_in,
                              void* d_out, int out_size, void* d_ws, size_t ws_size,
                              hipStream_t stream) {
  const float* x     = (const float*)d_in[0];
  const float* h     = (const float*)d_in[1];
  const float* state = (const float*)d_in[2];
  const float* Wf    = (const float*)d_in[3];
  const float* bfp   = (const float*)d_in[4];
  const float* Wi    = (const float*)d_in[5];
  const float* bip   = (const float*)d_in[6];
  const float* Wc    = (const float*)d_in[7];
  const float* bcp   = (const float*)d_in[8];
  const float* Wo    = (const float*)d_in[9];
  const float* bop   = (const float*)d_in[10];
  float* out = (float*)d_out;

  unsigned short* xh_t = (unsigned short*)d_ws;                      // 33.55 MB
  unsigned short* wt_t = (unsigned short*)((char*)d_ws +
                          (size_t)B_DIM * KDIM * 2);                 // 16.78 MB

  hipLaunchKernelGGL(pack_xh_kernel, dim3(2048), dim3(256), 0, stream,
                     x, h, xh_t);
  hipLaunchKernelGGL(transpose_w_kernel, dim3(128, 32), dim3(256), 0, stream,
                     Wf, Wi, Wc, Wo, wt_t);
  hipLaunchKernelGGL(lstm_gemm_kernel, dim3(16, 32), dim3(512), 0, stream,
                     xh_t, wt_t, state, bfp, bip, bcp, bop, out);
}